// Round 6
// baseline (45.774 us; speedup 1.0000x reference)
//
#include <hip/hip_runtime.h>

// DeepPoly affine transformer — fused single pass over weight.
// Identity: Wp@x + Wm@y = 0.5*( W@(x+y) - |W|@(y-x) )
//           Wp@y + Wm@x = 0.5*( W@(x+y) + |W|@(y-x) )
// mu folded: new_lower = bias + sum( wp*A + wm*B ), A=beta*l0, B=lmbda*u0+mu
//            new_upper = bias + sum( wp*B + wm*A )
// Per weight element: 1 abs + 4 FMA against 4 precomputed column streams.
//
// R6: ROWS=16 for the byte win (col stream 64->32 MB; W 134 MB fixed), but
// with register-pressure CONTROL (R5 lesson): k-loop NOT unrolled
// (#pragma unroll 1) and rows processed in 4 unrolled groups of 4 so only
// 4 W-float4s are in flight at once. Peak VGPR ~116 -> 4 waves/SIMD.
// SPLITK=4 keeps the grid at 1024 blocks (4/CU).

constexpr int N_OUT  = 4096;
constexpr int N_IN   = 8192;
constexpr int BLK    = 256;            // 4 waves
constexpr int ROWS   = 16;             // output rows per block
constexpr int RG     = 4;              // row group size (W loads in flight)
constexpr int SPLITK = 4;
constexpr int KSLICE = N_IN / SPLITK;        // 2048 columns per block
constexpr int KITER  = KSLICE / 4 / BLK;     // 2 float4 chunks per thread

__device__ __forceinline__ float4 ld4(const float* p) {
    return *reinterpret_cast<const float4*>(p);
}

__device__ __forceinline__ float waveRed(float v) {
#pragma unroll
    for (int off = 32; off > 0; off >>= 1)
        v += __shfl_xor(v, off, 64);
    return v;
}

// ---- pass 1: build the 4 fused column vectors into workspace ----
__global__ __launch_bounds__(256) void precompute_cols(
        const float* __restrict__ bounds,   // [2, N_IN]
        const float* __restrict__ bounds0,  // [2, N_IN]
        const float* __restrict__ beta,
        const float* __restrict__ lmbda,
        const float* __restrict__ mu,
        float* __restrict__ cols)           // [4, N_IN]
{
    const int i = blockIdx.x * 256 + threadIdx.x;
    if (i >= N_IN) return;
    const float l  = bounds[i],  u  = bounds[i + N_IN];
    const float l0 = bounds0[i], u0 = bounds0[i + N_IN];
    const float A  = beta[i] * l0;
    const float B  = fmaf(lmbda[i], u0, mu[i]);
    cols[i]             = l + u;   // s1
    cols[i + N_IN]      = u - l;   // d1  (>= 0)
    cols[i + 2 * N_IN]  = A + B;   // s2
    cols[i + 3 * N_IN]  = B - A;   // d2
}

// ---- pass 2: stream the weight once; write split-K partials ----
__global__ __launch_bounds__(BLK) void deeppoly_main(
        const float* __restrict__ W,
        const float* __restrict__ cols,
        float* __restrict__ partials)       // [SPLITK][N_OUT][4]
{
    const int t  = threadIdx.x;
    const int r0 = blockIdx.x * ROWS;
    const int sk = blockIdx.y;
    const int k0 = sk * KSLICE;

    const float* s1 = cols           + k0;
    const float* d1 = cols + N_IN    + k0;
    const float* s2 = cols + 2*N_IN  + k0;
    const float* d2 = cols + 3*N_IN  + k0;
    const float* Wb = W + (size_t)r0 * N_IN + k0;

    float aS[ROWS], aD[ROWS], aMS[ROWS], aMD[ROWS];
#pragma unroll
    for (int r = 0; r < ROWS; ++r) {
        aS[r] = 0.f; aD[r] = 0.f; aMS[r] = 0.f; aMD[r] = 0.f;
    }

#pragma unroll 1
    for (int k = 0; k < KITER; ++k) {
        const int c = (t + k * BLK) * 4;

        const float4 s1v = ld4(s1 + c);
        const float4 d1v = ld4(d1 + c);
        const float4 s2v = ld4(s2 + c);
        const float4 d2v = ld4(d2 + c);

#pragma unroll
        for (int g = 0; g < ROWS / RG; ++g) {
            // only RG=4 W-float4s in flight at once (16 dest VGPRs)
            float4 wv[RG];
#pragma unroll
            for (int j = 0; j < RG; ++j)
                wv[j] = ld4(Wb + (size_t)(g * RG + j) * N_IN + c);

#pragma unroll
            for (int j = 0; j < RG; ++j) {
                const int r = g * RG + j;

#define UPD(wc, s1c, d1c, s2c, d2c)                      \
                {                                        \
                    const float w_ = (wc);               \
                    const float a_ = fabsf(w_);          \
                    aS[r]  = fmaf(w_, (s1c), aS[r]);     \
                    aD[r]  = fmaf(a_, (d1c), aD[r]);     \
                    aMS[r] = fmaf(w_, (s2c), aMS[r]);    \
                    aMD[r] = fmaf(a_, (d2c), aMD[r]);    \
                }
                UPD(wv[j].x, s1v.x, d1v.x, s2v.x, d2v.x)
                UPD(wv[j].y, s1v.y, d1v.y, s2v.y, d2v.y)
                UPD(wv[j].z, s1v.z, d1v.z, s2v.z, d2v.z)
                UPD(wv[j].w, s1v.w, d1v.w, s2v.w, d2v.w)
#undef UPD
            }
        }
    }

    // ---- block reduction: wave shuffle-reduce, then LDS across 4 waves ----
    __shared__ float red[BLK / 64][ROWS][4];
    const int wave = t >> 6;
    const int lane = t & 63;

#pragma unroll
    for (int r = 0; r < ROWS; ++r) {
        const float vS  = waveRed(aS[r]);
        const float vD  = waveRed(aD[r]);
        const float vMS = waveRed(aMS[r]);
        const float vMD = waveRed(aMD[r]);
        if (lane == 0) {
            red[wave][r][0] = vS;
            red[wave][r][1] = vD;
            red[wave][r][2] = vMS;
            red[wave][r][3] = vMD;
        }
    }
    __syncthreads();

    // 64 threads write [row r, stream s] partial sums
    if (t < ROWS * 4) {
        const int r = t >> 2;
        const int s = t & 3;
        float acc = 0.f;
#pragma unroll
        for (int w = 0; w < BLK / 64; ++w)
            acc += red[w][r][s];
        partials[((size_t)sk * N_OUT + (r0 + r)) * 4 + s] = acc;
    }
}

// ---- pass 3: combine split-K partials + bias + tighter-bound select ----
__global__ __launch_bounds__(256) void deeppoly_epilogue(
        const float* __restrict__ partials, // [SPLITK][N_OUT][4]
        const float* __restrict__ bias,
        float* __restrict__ out)            // [2, N_OUT]
{
    const int i = blockIdx.x * 256 + threadIdx.x;
    if (i >= N_OUT) return;

    float4 p = ld4(partials + (size_t)i * 4);
#pragma unroll
    for (int sk = 1; sk < SPLITK; ++sk) {
        const float4 q = ld4(partials + ((size_t)sk * N_OUT + i) * 4);
        p.x += q.x; p.y += q.y; p.z += q.z; p.w += q.w;
    }
    const float bi = bias[i];
    const float lower     = fmaf(0.5f, p.x - p.y, bi);
    const float upper     = fmaf(0.5f, p.x + p.y, bi);
    const float new_lower = fmaf(0.5f, p.z - p.w, bi);
    const float new_upper = fmaf(0.5f, p.z + p.w, bi);

    out[i]         = fmaxf(lower, new_lower);
    out[N_OUT + i] = fminf(upper, new_upper);
}

extern "C" void kernel_launch(void* const* d_in, const int* in_sizes, int n_in,
                              void* d_out, int out_size, void* d_ws, size_t ws_size,
                              hipStream_t stream) {
    const float* W       = (const float*)d_in[0];
    const float* bias    = (const float*)d_in[1];
    const float* bounds  = (const float*)d_in[2];
    const float* bounds0 = (const float*)d_in[3];
    const float* beta    = (const float*)d_in[4];
    const float* lmbda   = (const float*)d_in[5];
    const float* mu      = (const float*)d_in[6];
    float* out      = (float*)d_out;
    float* cols     = (float*)d_ws;                       // 4*N_IN floats (128 KB)
    float* partials = (float*)d_ws + 4 * N_IN;            // SPLITK*N_OUT*4 floats (256 KB)

    precompute_cols<<<N_IN / 256, 256, 0, stream>>>(
        bounds, bounds0, beta, lmbda, mu, cols);

    dim3 grid(N_OUT / ROWS, SPLITK);
    deeppoly_main<<<grid, BLK, 0, stream>>>(W, cols, partials);

    deeppoly_epilogue<<<N_OUT / 256, 256, 0, stream>>>(partials, bias, out);
}

// Round 7
// 43.353 us; speedup vs baseline: 1.0558x; 1.0558x over previous
//
#include <hip/hip_runtime.h>

// DeepPoly affine transformer — fused single pass over weight.
// Identity: Wp@x + Wm@y = 0.5*( W@(x+y) - |W|@(y-x) )
//           Wp@y + Wm@x = 0.5*( W@(x+y) + |W|@(y-x) )
// mu folded: new_lower = bias + sum( wp*A + wm*B ), A=beta*l0, B=lmbda*u0+mu
//            new_upper = bias + sum( wp*B + wm*A )
// Per weight element: 1 abs + 4 FMA against 4 column streams.
//
// R7: ROWS=8 / SPLITK=4 / KITER=2.  Fixes the W-stream latency problem:
//  - cols staged to LDS once per block -> in-loop col reads are ds_read
//    (lgkmcnt), so they never force a vmcnt drain of in-flight W loads.
//  - all 16 W float4 loads issued before any use (after the staging
//    barrier); chunk-0 compute waits vmcnt(8) while chunk-1 stays in
//    flight.  R6's mistake (load->immediate-use per 4 rows) is gone.

constexpr int N_OUT  = 4096;
constexpr int N_IN   = 8192;
constexpr int BLK    = 256;             // 4 waves
constexpr int ROWS   = 8;               // output rows per block
constexpr int SPLITK = 4;
constexpr int KSLICE = N_IN / SPLITK;   // 2048 columns per block
constexpr int CHUNK  = BLK * 4;         // 1024 floats per chunk
constexpr int KITER  = KSLICE / CHUNK;  // 2
static_assert(KITER == 2, "pipeline hand-written for KITER == 2");

__device__ __forceinline__ float4 ld4(const float* p) {
    return *reinterpret_cast<const float4*>(p);
}

__device__ __forceinline__ float waveRed(float v) {
#pragma unroll
    for (int off = 32; off > 0; off >>= 1)
        v += __shfl_xor(v, off, 64);
    return v;
}

// ---- pass 1: build the 4 fused column vectors into workspace ----
__global__ __launch_bounds__(256) void precompute_cols(
        const float* __restrict__ bounds,   // [2, N_IN]
        const float* __restrict__ bounds0,  // [2, N_IN]
        const float* __restrict__ beta,
        const float* __restrict__ lmbda,
        const float* __restrict__ mu,
        float* __restrict__ cols)           // [4, N_IN]
{
    const int i = blockIdx.x * 256 + threadIdx.x;
    if (i >= N_IN) return;
    const float l  = bounds[i],  u  = bounds[i + N_IN];
    const float l0 = bounds0[i], u0 = bounds0[i + N_IN];
    const float A  = beta[i] * l0;
    const float B  = fmaf(lmbda[i], u0, mu[i]);
    cols[i]             = l + u;   // s1
    cols[i + N_IN]      = u - l;   // d1  (>= 0)
    cols[i + 2 * N_IN]  = A + B;   // s2
    cols[i + 3 * N_IN]  = B - A;   // d2
}

// ---- pass 2: stream the weight once; write split-K partials ----
__global__ __launch_bounds__(BLK) void deeppoly_main(
        const float* __restrict__ W,
        const float* __restrict__ cols,
        float* __restrict__ partials)       // [SPLITK][N_OUT][4]
{
    __shared__ __align__(16) float lds[4 * KSLICE];        // 32 KB col slice
    __shared__ float red[BLK / 64][ROWS][4];               // 0.5 KB

    const int t  = threadIdx.x;
    const int r0 = blockIdx.x * ROWS;
    const int sk = blockIdx.y;
    const int k0 = sk * KSLICE;

    // ---- stage the 4 col streams for this k-slice into LDS (once) ----
#pragma unroll
    for (int s = 0; s < 4; ++s) {
#pragma unroll
        for (int j = 0; j < KITER; ++j) {
            const int o = (j * BLK + t) * 4;
            *reinterpret_cast<float4*>(&lds[s * KSLICE + o]) =
                ld4(cols + s * N_IN + k0 + o);
        }
    }
    __syncthreads();   // drains only the small stage loads

    // ---- issue ALL W loads for both chunks before any use ----
    const float* Wb = W + (size_t)r0 * N_IN + k0;
    const int c0 = t * 4;
    const int c1 = CHUNK + t * 4;

    float4 w0[ROWS], w1[ROWS];
#pragma unroll
    for (int r = 0; r < ROWS; ++r)
        w0[r] = ld4(Wb + (size_t)r * N_IN + c0);
#pragma unroll
    for (int r = 0; r < ROWS; ++r)
        w1[r] = ld4(Wb + (size_t)r * N_IN + c1);

    float aS[ROWS], aD[ROWS], aMS[ROWS], aMD[ROWS];
#pragma unroll
    for (int r = 0; r < ROWS; ++r) {
        aS[r] = 0.f; aD[r] = 0.f; aMS[r] = 0.f; aMD[r] = 0.f;
    }

#define UPD(wc, s1c, d1c, s2c, d2c)                      \
    {                                                    \
        const float w_ = (wc);                           \
        const float a_ = fabsf(w_);                      \
        aS[r]  = fmaf(w_, (s1c), aS[r]);                 \
        aD[r]  = fmaf(a_, (d1c), aD[r]);                 \
        aMS[r] = fmaf(w_, (s2c), aMS[r]);                \
        aMD[r] = fmaf(a_, (d2c), aMD[r]);                \
    }

#define PHASE(wv, cof)                                                        \
    {                                                                         \
        const float4 s1v = *reinterpret_cast<const float4*>(&lds[0 * KSLICE + (cof)]); \
        const float4 d1v = *reinterpret_cast<const float4*>(&lds[1 * KSLICE + (cof)]); \
        const float4 s2v = *reinterpret_cast<const float4*>(&lds[2 * KSLICE + (cof)]); \
        const float4 d2v = *reinterpret_cast<const float4*>(&lds[3 * KSLICE + (cof)]); \
        _Pragma("unroll")                                                     \
        for (int r = 0; r < ROWS; ++r) {                                      \
            UPD(wv[r].x, s1v.x, d1v.x, s2v.x, d2v.x)                          \
            UPD(wv[r].y, s1v.y, d1v.y, s2v.y, d2v.y)                          \
            UPD(wv[r].z, s1v.z, d1v.z, s2v.z, d2v.z)                          \
            UPD(wv[r].w, s1v.w, d1v.w, s2v.w, d2v.w)                          \
        }                                                                     \
    }

    PHASE(w0, c0)   // waits vmcnt(8): w1 stays in flight
    PHASE(w1, c1)   // waits vmcnt(0)

#undef PHASE
#undef UPD

    // ---- block reduction: wave shuffle-reduce, then LDS across 4 waves ----
    const int wave = t >> 6;
    const int lane = t & 63;

#pragma unroll
    for (int r = 0; r < ROWS; ++r) {
        const float vS  = waveRed(aS[r]);
        const float vD  = waveRed(aD[r]);
        const float vMS = waveRed(aMS[r]);
        const float vMD = waveRed(aMD[r]);
        if (lane == 0) {
            red[wave][r][0] = vS;
            red[wave][r][1] = vD;
            red[wave][r][2] = vMS;
            red[wave][r][3] = vMD;
        }
    }
    __syncthreads();

    // 32 threads write [row r, stream s] partial sums
    if (t < ROWS * 4) {
        const int r = t >> 2;
        const int s = t & 3;
        float acc = 0.f;
#pragma unroll
        for (int w = 0; w < BLK / 64; ++w)
            acc += red[w][r][s];
        partials[((size_t)sk * N_OUT + (r0 + r)) * 4 + s] = acc;
    }
}

// ---- pass 3: combine split-K partials + bias + tighter-bound select ----
__global__ __launch_bounds__(256) void deeppoly_epilogue(
        const float* __restrict__ partials, // [SPLITK][N_OUT][4]
        const float* __restrict__ bias,
        float* __restrict__ out)            // [2, N_OUT]
{
    const int i = blockIdx.x * 256 + threadIdx.x;
    if (i >= N_OUT) return;

    float4 p = ld4(partials + (size_t)i * 4);
#pragma unroll
    for (int sk = 1; sk < SPLITK; ++sk) {
        const float4 q = ld4(partials + ((size_t)sk * N_OUT + i) * 4);
        p.x += q.x; p.y += q.y; p.z += q.z; p.w += q.w;
    }
    const float bi = bias[i];
    const float lower     = fmaf(0.5f, p.x - p.y, bi);
    const float upper     = fmaf(0.5f, p.x + p.y, bi);
    const float new_lower = fmaf(0.5f, p.z - p.w, bi);
    const float new_upper = fmaf(0.5f, p.z + p.w, bi);

    out[i]         = fmaxf(lower, new_lower);
    out[N_OUT + i] = fminf(upper, new_upper);
}

extern "C" void kernel_launch(void* const* d_in, const int* in_sizes, int n_in,
                              void* d_out, int out_size, void* d_ws, size_t ws_size,
                              hipStream_t stream) {
    const float* W       = (const float*)d_in[0];
    const float* bias    = (const float*)d_in[1];
    const float* bounds  = (const float*)d_in[2];
    const float* bounds0 = (const float*)d_in[3];
    const float* beta    = (const float*)d_in[4];
    const float* lmbda   = (const float*)d_in[5];
    const float* mu      = (const float*)d_in[6];
    float* out      = (float*)d_out;
    float* cols     = (float*)d_ws;                 // 4*N_IN floats (128 KB)
    float* partials = (float*)d_ws + 4 * N_IN;      // SPLITK*N_OUT*4 floats (256 KB)

    precompute_cols<<<N_IN / 256, 256, 0, stream>>>(
        bounds, bounds0, beta, lmbda, mu, cols);

    dim3 grid(N_OUT / ROWS, SPLITK);
    deeppoly_main<<<grid, BLK, 0, stream>>>(W, cols, partials);

    deeppoly_epilogue<<<N_OUT / 256, 256, 0, stream>>>(partials, bias, out);
}

// Round 8
// 41.381 us; speedup vs baseline: 1.1061x; 1.0476x over previous
//
#include <hip/hip_runtime.h>

// DeepPoly affine transformer — fused single pass over weight.
// Identity: Wp@x + Wm@y = 0.5*( W@(x+y) - |W|@(y-x) )
//           Wp@y + Wm@x = 0.5*( W@(x+y) + |W|@(y-x) )
// mu folded: new_lower = bias + sum( wp*A + wm*B ), A=beta*l0, B=lmbda*u0+mu
//            new_upper = bias + sum( wp*B + wm*A )
// Per weight element: 1 abs + 4 FMA against 4 column streams.
//
// R8: rolling register double-buffer pipeline (T4 principle: never drain
// vmcnt to 0 in steady state).  In-flight depth model: 6.3 TB/s needs
// ~9.2 KB/CU in flight at ~900cy HBM latency; R4/R7's drain-y patterns
// averaged ~8 loads/wave -> 4.2 TB/s (matches measured 4.3).  Here every
// compute window has >=12 newer loads in flight.  No LDS, no barriers in
// the hot path; cols issued before W per chunk so the vmcnt FIFO retires
// them first.

constexpr int N_OUT  = 4096;
constexpr int N_IN   = 8192;
constexpr int BLK    = 256;             // 4 waves
constexpr int ROWS   = 8;               // output rows per block
constexpr int SPLITK = 2;
constexpr int KSLICE = N_IN / SPLITK;   // 4096 columns per block
constexpr int CHUNK  = BLK * 4;         // 1024 floats per chunk
constexpr int KITER  = KSLICE / CHUNK;  // 4 chunks, 2 A/B pairs
static_assert(KITER % 2 == 0, "pairwise pipeline");

__device__ __forceinline__ float4 ld4(const float* p) {
    return *reinterpret_cast<const float4*>(p);
}

__device__ __forceinline__ float waveRed(float v) {
#pragma unroll
    for (int off = 32; off > 0; off >>= 1)
        v += __shfl_xor(v, off, 64);
    return v;
}

// ---- pass 1: build the 4 fused column vectors into workspace ----
__global__ __launch_bounds__(256) void precompute_cols(
        const float* __restrict__ bounds,   // [2, N_IN]
        const float* __restrict__ bounds0,  // [2, N_IN]
        const float* __restrict__ beta,
        const float* __restrict__ lmbda,
        const float* __restrict__ mu,
        float* __restrict__ cols)           // [4, N_IN]
{
    const int i = blockIdx.x * 256 + threadIdx.x;
    if (i >= N_IN) return;
    const float l  = bounds[i],  u  = bounds[i + N_IN];
    const float l0 = bounds0[i], u0 = bounds0[i + N_IN];
    const float A  = beta[i] * l0;
    const float B  = fmaf(lmbda[i], u0, mu[i]);
    cols[i]             = l + u;   // s1
    cols[i + N_IN]      = u - l;   // d1  (>= 0)
    cols[i + 2 * N_IN]  = A + B;   // s2
    cols[i + 3 * N_IN]  = B - A;   // d2
}

// ---- pass 2: stream the weight once; write split-K partials ----
__global__ __launch_bounds__(BLK) void deeppoly_main(
        const float* __restrict__ W,
        const float* __restrict__ cols,
        float* __restrict__ partials)       // [SPLITK][N_OUT][4]
{
    const int t  = threadIdx.x;
    const int r0 = blockIdx.x * ROWS;
    const int sk = blockIdx.y;
    const int k0 = sk * KSLICE;

    const float* Wb = W + (size_t)r0 * N_IN + k0;
    const float* cb0 = cols + 0 * N_IN + k0;
    const float* cb1 = cols + 1 * N_IN + k0;
    const float* cb2 = cols + 2 * N_IN + k0;
    const float* cb3 = cols + 3 * N_IN + k0;

    float4 wA[ROWS], wB[ROWS];
    float4 cA[4],   cB[4];

    float aS[ROWS], aD[ROWS], aMS[ROWS], aMD[ROWS];
#pragma unroll
    for (int r = 0; r < ROWS; ++r) {
        aS[r] = 0.f; aD[r] = 0.f; aMS[r] = 0.f; aMD[r] = 0.f;
    }

    // cols first: vmcnt FIFO retires the (L2-hot) col loads before the
    // HBM W loads, so waiting on W implies cols ready for free.
#define ISSUE(wv, cv, j)                                          \
    {                                                             \
        const int c_ = (j) * CHUNK + t * 4;                       \
        cv[0] = ld4(cb0 + c_);                                    \
        cv[1] = ld4(cb1 + c_);                                    \
        cv[2] = ld4(cb2 + c_);                                    \
        cv[3] = ld4(cb3 + c_);                                    \
        _Pragma("unroll")                                         \
        for (int r = 0; r < ROWS; ++r)                            \
            wv[r] = ld4(Wb + (size_t)r * N_IN + c_);              \
    }

#define UPD(wc, s1c, d1c, s2c, d2c)                      \
    {                                                    \
        const float w_ = (wc);                           \
        const float a_ = fabsf(w_);                      \
        aS[r]  = fmaf(w_, (s1c), aS[r]);                 \
        aD[r]  = fmaf(a_, (d1c), aD[r]);                 \
        aMS[r] = fmaf(w_, (s2c), aMS[r]);                \
        aMD[r] = fmaf(a_, (d2c), aMD[r]);                \
    }

#define COMPUTE(wv, cv)                                           \
    {                                                             \
        _Pragma("unroll")                                         \
        for (int r = 0; r < ROWS; ++r) {                          \
            UPD(wv[r].x, cv[0].x, cv[1].x, cv[2].x, cv[3].x)      \
            UPD(wv[r].y, cv[0].y, cv[1].y, cv[2].y, cv[3].y)      \
            UPD(wv[r].z, cv[0].z, cv[1].z, cv[2].z, cv[3].z)      \
            UPD(wv[r].w, cv[0].w, cv[1].w, cv[2].w, cv[3].w)      \
        }                                                         \
    }

    ISSUE(wA, cA, 0)
    ISSUE(wB, cB, 1)

#pragma unroll 1
    for (int p = 0; p < KITER / 2; ++p) {
        COMPUTE(wA, cA)                       // waits w/ B(+next) in flight
        if (2 * p + 2 < KITER) { ISSUE(wA, cA, 2 * p + 2) }
        COMPUTE(wB, cB)                       // waits w/ A-next in flight
        if (2 * p + 3 < KITER) { ISSUE(wB, cB, 2 * p + 3) }
    }

#undef COMPUTE
#undef UPD
#undef ISSUE

    // ---- block reduction: wave shuffle-reduce, then LDS across 4 waves ----
    __shared__ float red[BLK / 64][ROWS][4];
    const int wave = t >> 6;
    const int lane = t & 63;

#pragma unroll
    for (int r = 0; r < ROWS; ++r) {
        const float vS  = waveRed(aS[r]);
        const float vD  = waveRed(aD[r]);
        const float vMS = waveRed(aMS[r]);
        const float vMD = waveRed(aMD[r]);
        if (lane == 0) {
            red[wave][r][0] = vS;
            red[wave][r][1] = vD;
            red[wave][r][2] = vMS;
            red[wave][r][3] = vMD;
        }
    }
    __syncthreads();

    if (t < ROWS * 4) {
        const int r = t >> 2;
        const int s = t & 3;
        float acc = 0.f;
#pragma unroll
        for (int w = 0; w < BLK / 64; ++w)
            acc += red[w][r][s];
        partials[((size_t)sk * N_OUT + (r0 + r)) * 4 + s] = acc;
    }
}

// ---- pass 3: combine split-K partials + bias + tighter-bound select ----
__global__ __launch_bounds__(256) void deeppoly_epilogue(
        const float* __restrict__ partials, // [SPLITK][N_OUT][4]
        const float* __restrict__ bias,
        float* __restrict__ out)            // [2, N_OUT]
{
    const int i = blockIdx.x * 256 + threadIdx.x;
    if (i >= N_OUT) return;

    float4 p = ld4(partials + (size_t)i * 4);
#pragma unroll
    for (int sk = 1; sk < SPLITK; ++sk) {
        const float4 q = ld4(partials + ((size_t)sk * N_OUT + i) * 4);
        p.x += q.x; p.y += q.y; p.z += q.z; p.w += q.w;
    }
    const float bi = bias[i];
    const float lower     = fmaf(0.5f, p.x - p.y, bi);
    const float upper     = fmaf(0.5f, p.x + p.y, bi);
    const float new_lower = fmaf(0.5f, p.z - p.w, bi);
    const float new_upper = fmaf(0.5f, p.z + p.w, bi);

    out[i]         = fmaxf(lower, new_lower);
    out[N_OUT + i] = fminf(upper, new_upper);
}

extern "C" void kernel_launch(void* const* d_in, const int* in_sizes, int n_in,
                              void* d_out, int out_size, void* d_ws, size_t ws_size,
                              hipStream_t stream) {
    const float* W       = (const float*)d_in[0];
    const float* bias    = (const float*)d_in[1];
    const float* bounds  = (const float*)d_in[2];
    const float* bounds0 = (const float*)d_in[3];
    const float* beta    = (const float*)d_in[4];
    const float* lmbda   = (const float*)d_in[5];
    const float* mu      = (const float*)d_in[6];
    float* out      = (float*)d_out;
    float* cols     = (float*)d_ws;                 // 4*N_IN floats (128 KB)
    float* partials = (float*)d_ws + 4 * N_IN;      // SPLITK*N_OUT*4 floats (128 KB)

    precompute_cols<<<N_IN / 256, 256, 0, stream>>>(
        bounds, bounds0, beta, lmbda, mu, cols);

    dim3 grid(N_OUT / ROWS, SPLITK);
    deeppoly_main<<<grid, BLK, 0, stream>>>(W, cols, partials);

    deeppoly_epilogue<<<N_OUT / 256, 256, 0, stream>>>(partials, bias, out);
}